// Round 14
// baseline (184.705 us; speedup 1.0000x reference)
//
#include <hip/hip_runtime.h>

typedef __attribute__((ext_vector_type(4))) float f32x4;
typedef __attribute__((ext_vector_type(2))) float f32x2;
typedef __attribute__((ext_vector_type(8))) short bf16x8;

#define MEMBAR() asm volatile("" ::: "memory")

__device__ __forceinline__ unsigned short f2bf(float f) {
  unsigned int u = __builtin_bit_cast(unsigned int, f);
  u += 0x7FFFu + ((u >> 16) & 1u);   // RTNE
  return (unsigned short)(u >> 16);
}

// ---- K0a: P[b][h] = b_attn[h] + dot(W_attn[h, 0:512], hidden[b, :])
__global__ __launch_bounds__(256) void k_prep_p(
    const float* __restrict__ hidden, const float* __restrict__ W,
    const float* __restrict__ bias, float* __restrict__ P) {
  __shared__ float hsh[512];
  const int b = blockIdx.x;
  for (int i = threadIdx.x; i < 512; i += 256) hsh[i] = hidden[b * 512 + i];
  __syncthreads();
  for (int h = threadIdx.x; h < 512; h += 256) {
    const float* wr = W + (long)h * 1536;
    float s = 0.f;
#pragma unroll 4
    for (int f = 0; f < 512; f += 4) {
      float4 wv = *reinterpret_cast<const float4*>(wr + f);
      s += wv.x * hsh[f] + wv.y * hsh[f + 1] + wv.z * hsh[f + 2] + wv.w * hsh[f + 3];
    }
    P[b * 512 + h] = bias[h] + s;
  }
}

// ---- K0b: W2t[kb][h][kk] = bf16(W_attn[h][512 + kb*32 + kk]),  kb<32, h<512, kk<32
__global__ __launch_bounds__(256) void k_prep_w(
    const float* __restrict__ W, unsigned short* __restrict__ W2t) {
  const int id = blockIdx.x * 256 + threadIdx.x;  // 65536 threads, 8 elems each
  const int kk8 = (id & 3) * 8;
  const int h = (id >> 2) & 511;
  const int kb = id >> 11;
  const float* src = W + (long)h * 1536 + 512 + kb * 32 + kk8;
  float4 a = *reinterpret_cast<const float4*>(src);
  float4 c = *reinterpret_cast<const float4*>(src + 4);
  union { unsigned short u[8]; bf16x8 v; } o;
  o.u[0] = f2bf(a.x); o.u[1] = f2bf(a.y); o.u[2] = f2bf(a.z); o.u[3] = f2bf(a.w);
  o.u[4] = f2bf(c.x); o.u[5] = f2bf(c.y); o.u[6] = f2bf(c.z); o.u[7] = f2bf(c.w);
  *reinterpret_cast<bf16x8*>(W2t + (long)kb * 16384 + h * 32 + kk8) = o.v;
}

// ---- K1: fused GEMM + tanh + v-reduce -> logits (complete per block)
// 2048 blocks x 512 thr = 8 waves; wave w: 32 rows x cols [w*64, w*64+64).
// Block covers 32 rows x ALL 512 h -> enc read once, logits complete.
// Round-9 champion pipeline verbatim (reg-staged bf16 LDS ring x4,
// cvt-on-write, one raw s_barrier + lgkmcnt(0)/iter, no vmcnt drains),
// but wave tile 32x64 -> acc[2][4] = 32 AGPR. Per-thread regs ~105 =>
// __launch_bounds__(512,4): TWO blocks/CU resident (16 waves, 50% occ),
// 4 waves/SIMD from 2 independent barrier groups hide each other's chains.
__global__ __launch_bounds__(512, 4) void k_main(
    const float* __restrict__ enc, const short* __restrict__ W2t,
    const float* __restrict__ P, const float* __restrict__ v,
    float* __restrict__ logits) {
  __shared__ short As[4][1024];        // 4 sub-bufs x [32 rows][32 k] bf16 = 8 KB
  __shared__ float attred[32][8];

  const int tid = threadIdx.x;
  const int lane = tid & 63;
  const int w = tid >> 6;               // 0..7: col panel [w*64, +64)
  const int hl = lane & 15, kg = lane >> 4;
  const long rowbase = (long)blockIdx.x * 32;
  const int b = (int)(rowbase >> 12);   // 32 | 4096

  // staging: thread -> row r = tid>>4 (0..31), 2 floats at k = (tid&15)*2
  const int r = tid >> 4, c = tid & 15;
  const float* ga = enc + (rowbase + r) * 1024 + c * 2;
  // swizzled write (shorts): 16B chunk (c>>2) ^ (r&3), within-chunk (c&3)*2
  const int wr_off = r * 32 + (((c >> 2) ^ (r & 3)) << 3) + ((c & 3) << 1);
  // frag read (shorts): row = mi*16+hl, chunk = kg ^ (hl&3)   [mi-invariant]
  const int base_f = hl * 32 + ((kg ^ (hl & 3)) << 3);
  // B: h = w*64 + ni*16 + hl; elem = kb*16384 + h*32 + kg*8
  const short* bp = W2t + (w * 64 + hl) * 32 + kg * 8;

  f32x4 acc[2][4];
#pragma unroll
  for (int mi = 0; mi < 2; ++mi)
#pragma unroll
    for (int ni = 0; ni < 4; ++ni) acc[mi][ni] = (f32x4){0.f, 0.f, 0.f, 0.f};

  bf16x8 Ba[4], Bb[4];
  f32x2 rawE, rawO;

#define CVT2W(BUF, RAW) {                                             \
    union { unsigned short u[2]; unsigned int d; } _u;                \
    _u.u[0] = f2bf((RAW)[0]); _u.u[1] = f2bf((RAW)[1]);               \
    *reinterpret_cast<unsigned int*>(&As[(BUF)][wr_off]) = _u.d;      \
  }
#define LOADB(DST, KB) {                                              \
    const short* _k = bp + (KB) * 16384;                              \
    DST[0] = *reinterpret_cast<const bf16x8*>(_k);                    \
    DST[1] = *reinterpret_cast<const bf16x8*>(_k + 512);              \
    DST[2] = *reinterpret_cast<const bf16x8*>(_k + 1024);             \
    DST[3] = *reinterpret_cast<const bf16x8*>(_k + 1536);             \
  }
// iter J: barrier; gload tile J+2 -> RAWOUT; B(J+1) -> BOUT; 8 MFMA from
// buf[J&3] x BIN; cvt RAWIN (tile J+1, loaded at J-1) -> buf[(J+1)&3]; lgkm(0)
#define K_ITER(J, RAWIN, RAWOUT, BIN, BOUT, DO_G, DO_B, DO_CVT) {     \
    MEMBAR();                                                         \
    __builtin_amdgcn_s_barrier();                                     \
    MEMBAR();                                                         \
    if (DO_G) RAWOUT = *reinterpret_cast<const f32x2*>(ga + ((J) + 2) * 32); \
    if (DO_B) LOADB(BOUT, (J) + 1);                                   \
    MEMBAR();                                                         \
    const short* _ab = &As[(J) & 3][0];                               \
    bf16x8 _f0 = *reinterpret_cast<const bf16x8*>(_ab + base_f);      \
    bf16x8 _f1 = *reinterpret_cast<const bf16x8*>(_ab + base_f + 512);\
    acc[0][0] = __builtin_amdgcn_mfma_f32_16x16x32_bf16(_f0, BIN[0], acc[0][0], 0, 0, 0); \
    acc[0][1] = __builtin_amdgcn_mfma_f32_16x16x32_bf16(_f0, BIN[1], acc[0][1], 0, 0, 0); \
    acc[0][2] = __builtin_amdgcn_mfma_f32_16x16x32_bf16(_f0, BIN[2], acc[0][2], 0, 0, 0); \
    acc[0][3] = __builtin_amdgcn_mfma_f32_16x16x32_bf16(_f0, BIN[3], acc[0][3], 0, 0, 0); \
    acc[1][0] = __builtin_amdgcn_mfma_f32_16x16x32_bf16(_f1, BIN[0], acc[1][0], 0, 0, 0); \
    acc[1][1] = __builtin_amdgcn_mfma_f32_16x16x32_bf16(_f1, BIN[1], acc[1][1], 0, 0, 0); \
    acc[1][2] = __builtin_amdgcn_mfma_f32_16x16x32_bf16(_f1, BIN[2], acc[1][2], 0, 0, 0); \
    acc[1][3] = __builtin_amdgcn_mfma_f32_16x16x32_bf16(_f1, BIN[3], acc[1][3], 0, 0, 0); \
    if (DO_CVT) CVT2W(((J) + 1) & 3, RAWIN);                          \
    asm volatile("s_waitcnt lgkmcnt(0)" ::: "memory");                \
  }

  // prologue: tile0 -> buf0; tile1 -> rawO; B(0) -> Ba
  {
    f32x2 t0 = *reinterpret_cast<const f32x2*>(ga);
    CVT2W(0, t0);
  }
  rawO = *reinterpret_cast<const f32x2*>(ga + 32);
  LOADB(Ba, 0);
  __syncthreads();

#pragma unroll 1
  for (int p = 0; p < 15; ++p) {
    const int j = p * 2;
    K_ITER(j,     rawO, rawE, Ba, Bb, 1, 1, 1)
    K_ITER(j + 1, rawE, rawO, Bb, Ba, 1, 1, 1)
  }
  K_ITER(30, rawO, rawE, Ba, Bb, 0, 1, 1)
  K_ITER(31, rawE, rawO, Bb, Ba, 0, 0, 0)

#undef K_ITER
#undef LOADB
#undef CVT2W

  // epilogue: x = acc + P[b][h]; part += v[h]*tanh(x); reduce over hl lanes
  float part[2][4];
#pragma unroll
  for (int mi = 0; mi < 2; ++mi)
#pragma unroll
    for (int rr = 0; rr < 4; ++rr) part[mi][rr] = 0.f;

#pragma unroll
  for (int ni = 0; ni < 4; ++ni) {
    const int h = w * 64 + ni * 16 + hl;
    const float ph = P[b * 512 + h];
    const float vh = v[h];
#pragma unroll
    for (int mi = 0; mi < 2; ++mi)
#pragma unroll
      for (int rr = 0; rr < 4; ++rr) {
        float x = acc[mi][ni][rr] + ph;
        float e = __expf(2.f * x);
        part[mi][rr] += vh * (1.f - 2.f * __frcp_rn(e + 1.f));
      }
  }
#pragma unroll
  for (int off = 1; off < 16; off <<= 1)
#pragma unroll
    for (int mi = 0; mi < 2; ++mi)
#pragma unroll
      for (int rr = 0; rr < 4; ++rr)
        part[mi][rr] += __shfl_xor(part[mi][rr], off, 16);

  if (hl == 0) {
#pragma unroll
    for (int mi = 0; mi < 2; ++mi)
#pragma unroll
      for (int rr = 0; rr < 4; ++rr)
        attred[mi * 16 + kg * 4 + rr][w] = part[mi][rr];
  }
  __syncthreads();
  if (tid < 32) {
    const float* a = attred[tid];
    logits[rowbase + tid] = ((a[0] + a[1]) + (a[2] + a[3])) +
                            ((a[4] + a[5]) + (a[6] + a[7]));
  }
}

// ---- K2: softmax over S=4096 per batch row
__global__ __launch_bounds__(256) void k_softmax(
    const float* __restrict__ logits, float* __restrict__ out) {
  const int b = blockIdx.x;
  const int t = threadIdx.x;
  const int wid = t >> 6, lane = t & 63;
  const float* L = logits + b * 4096;
  __shared__ float rmax[4], rsum[4];
  float lv[16];
  float m = -1e30f;
#pragma unroll
  for (int i = 0; i < 16; ++i) {
    lv[i] = L[t + i * 256];
    m = fmaxf(m, lv[i]);
  }
#pragma unroll
  for (int off = 32; off >= 1; off >>= 1) m = fmaxf(m, __shfl_xor(m, off));
  if (lane == 0) rmax[wid] = m;
  __syncthreads();
  m = fmaxf(fmaxf(rmax[0], rmax[1]), fmaxf(rmax[2], rmax[3]));
  float s = 0.f;
#pragma unroll
  for (int i = 0; i < 16; ++i) {
    lv[i] = __expf(lv[i] - m);
    s += lv[i];
  }
#pragma unroll
  for (int off = 32; off >= 1; off >>= 1) s += __shfl_xor(s, off);
  if (lane == 0) rsum[wid] = s;
  __syncthreads();
  s = rsum[0] + rsum[1] + rsum[2] + rsum[3];
  float inv = 1.0f / s;
#pragma unroll
  for (int i = 0; i < 16; ++i) out[b * 4096 + t + i * 256] = lv[i] * inv;
}

extern "C" void kernel_launch(void* const* d_in, const int* in_sizes, int n_in,
                              void* d_out, int out_size, void* d_ws, size_t ws_size,
                              hipStream_t stream) {
  const float* hidden = (const float*)d_in[0];   // [16,512]
  const float* enc    = (const float*)d_in[1];   // [16,4096,1024]
  const float* W      = (const float*)d_in[2];   // [512,1536]
  const float* bias   = (const float*)d_in[3];   // [512]
  const float* v      = (const float*)d_in[4];   // [512]
  float* out = (float*)d_out;                    // [16,4096]

  char* ws = (char*)d_ws;
  float* P = (float*)ws;                                       // 32 KB
  unsigned short* W2t = (unsigned short*)(ws + 32768);         // 1 MB
  float* logits = (float*)(ws + 32768 + 1048576);              // 256 KB

  k_prep_p<<<16, 256, 0, stream>>>(hidden, W, bias, P);
  k_prep_w<<<256, 256, 0, stream>>>(W, W2t);
  k_main<<<2048, 512, 0, stream>>>(enc, (const short*)W2t, P, v, logits);
  k_softmax<<<16, 256, 0, stream>>>(logits, out);
}

// Round 15
// 120.355 us; speedup vs baseline: 1.5347x; 1.5347x over previous
//
#include <hip/hip_runtime.h>

typedef __attribute__((ext_vector_type(4))) float f32x4;
typedef __attribute__((ext_vector_type(8))) short bf16x8;
typedef __attribute__((ext_vector_type(4))) short bf16x4;

#define MEMBAR() asm volatile("" ::: "memory")

__device__ __forceinline__ unsigned short f2bf(float f) {
  unsigned int u = __builtin_bit_cast(unsigned int, f);
  u += 0x7FFFu + ((u >> 16) & 1u);   // RTNE
  return (unsigned short)(u >> 16);
}

// ---- K0: fused prep. Blocks 0..255: W2 repack -> bf16 [kb][h][kk].
//          Blocks 256..287: P[b][h] = bias[h] + dot(W[h,0:512], hidden[b,:]),
//          one h-dot per thread (same FP order as before; 2 blocks per batch).
__global__ __launch_bounds__(256) void k_prep(
    const float* __restrict__ W, const float* __restrict__ hidden,
    const float* __restrict__ bias, unsigned short* __restrict__ W2t,
    float* __restrict__ P) {
  __shared__ float hsh[512];
  const int bid = blockIdx.x;
  const int tid = threadIdx.x;
  if (bid < 256) {
    const int id = bid * 256 + tid;  // 65536 threads, 8 elems each
    const int kk8 = (id & 3) * 8;
    const int h = (id >> 2) & 511;
    const int kb = id >> 11;
    const float* src = W + (long)h * 1536 + 512 + kb * 32 + kk8;
    float4 a = *reinterpret_cast<const float4*>(src);
    float4 c = *reinterpret_cast<const float4*>(src + 4);
    union { unsigned short u[8]; bf16x8 v; } o;
    o.u[0] = f2bf(a.x); o.u[1] = f2bf(a.y); o.u[2] = f2bf(a.z); o.u[3] = f2bf(a.w);
    o.u[4] = f2bf(c.x); o.u[5] = f2bf(c.y); o.u[6] = f2bf(c.z); o.u[7] = f2bf(c.w);
    *reinterpret_cast<bf16x8*>(W2t + (long)kb * 16384 + h * 32 + kk8) = o.v;
  } else {
    const int bid2 = bid - 256;          // 0..31
    const int b = bid2 >> 1;             // 0..15
    const int h = (bid2 & 1) * 256 + tid;
    for (int i = tid; i < 512; i += 256) hsh[i] = hidden[b * 512 + i];
    __syncthreads();
    const float* wr = W + (long)h * 1536;
    float s = 0.f;
#pragma unroll 4
    for (int f = 0; f < 512; f += 4) {
      float4 wv = *reinterpret_cast<const float4*>(wr + f);
      s += wv.x * hsh[f] + wv.y * hsh[f + 1] + wv.z * hsh[f + 2] + wv.w * hsh[f + 3];
    }
    P[b * 512 + h] = bias[h] + s;
  }
}

// ---- K1: fused GEMM + tanh + v-reduce -> logits (round-9 champion, verbatim)
// 1024 blocks x 512 thr = 8 waves; wave w: 64 rows x cols [w*64, w*64+64).
// Block covers all 512 h -> enc read once, logits complete (no partials).
// A tile (64 x BK=32) reg-staged f32 -> cvt bf16 -> LDS, 4-buffer ring, ONE raw
// s_barrier per iter (never a vmcnt drain). cvt+ds_write AFTER the MFMAs so the
// A gload->use distance is ~2 iters; B (L2) prefetched 1 iter ahead.
__global__ __launch_bounds__(512, 2) void k_main(
    const float* __restrict__ enc, const short* __restrict__ W2t,
    const float* __restrict__ P, const float* __restrict__ v,
    float* __restrict__ logits) {
  __shared__ short As[4][2048];        // 4 bufs x [64 rows][32 k] bf16 = 16 KB
  __shared__ float attred[64][8];

  const int tid = threadIdx.x;
  const int lane = tid & 63;
  const int w = tid >> 6;               // 0..7: col panel
  const int hl = lane & 15, kg = lane >> 4;
  const long rowbase = (long)blockIdx.x * 64;
  const int b = (int)(rowbase >> 12);   // 64 | 4096

  // staging: thread -> row r = tid>>3, chunk c = tid&7 (4 floats at k=c*4)
  const int r = tid >> 3, c = tid & 7;
  const f32x4* gp = reinterpret_cast<const f32x4*>(enc + (rowbase + r) * 1024) + c;
  // swizzled write offset (shorts): slot' = (c>>1) ^ ((r>>1)&3), half = c&1
  const int wr_off = r * 32 + ((((c >> 1) ^ ((r >> 1) & 3)) << 3)) + ((c & 1) << 2);
  // frag read offset (shorts): row = mi*16+hl, slot = kg ^ ((hl>>1)&3)
  const int base_f = hl * 32 + ((kg ^ ((hl >> 1) & 3)) << 3);
  // B: h = w*64 + ni*16 + hl; elem = kb*16384 + h*32 + kg*8
  const short* bp = W2t + (w * 64 + hl) * 32 + kg * 8;

  f32x4 acc[4][4];
#pragma unroll
  for (int mi = 0; mi < 4; ++mi)
#pragma unroll
    for (int ni = 0; ni < 4; ++ni) acc[mi][ni] = (f32x4){0.f, 0.f, 0.f, 0.f};

  bf16x8 Ba[4], Bb[4];
  f32x4 rawE, rawO;

#define CVT4W(BUF, RAW) {                                             \
    union { __bf16 h[4]; bf16x4 s; } _u;                              \
    _u.h[0] = (__bf16)(RAW)[0]; _u.h[1] = (__bf16)(RAW)[1];           \
    _u.h[2] = (__bf16)(RAW)[2]; _u.h[3] = (__bf16)(RAW)[3];           \
    *reinterpret_cast<bf16x4*>(&As[(BUF)][wr_off]) = _u.s;            \
  }
#define LOADB(DST, KB) {                                              \
    const short* _k = bp + (KB) * 16384;                              \
    DST[0] = *reinterpret_cast<const bf16x8*>(_k);                    \
    DST[1] = *reinterpret_cast<const bf16x8*>(_k + 512);              \
    DST[2] = *reinterpret_cast<const bf16x8*>(_k + 1024);             \
    DST[3] = *reinterpret_cast<const bf16x8*>(_k + 1536);             \
  }
#define K_ITER(J, RAWIN, RAWOUT, BIN, BOUT, DO_G, DO_B, DO_CVT) {     \
    MEMBAR();                                                         \
    __builtin_amdgcn_s_barrier();                                     \
    MEMBAR();                                                         \
    if (DO_G) RAWOUT = gp[((J) + 2) * 8];                             \
    if (DO_B) LOADB(BOUT, (J) + 1);                                   \
    MEMBAR();                                                         \
    const short* _ab = &As[(J) & 3][0];                               \
    bf16x8 _f0 = *reinterpret_cast<const bf16x8*>(_ab + base_f);      \
    bf16x8 _f1 = *reinterpret_cast<const bf16x8*>(_ab + base_f + 512);\
    bf16x8 _f2 = *reinterpret_cast<const bf16x8*>(_ab + base_f + 1024);\
    bf16x8 _f3 = *reinterpret_cast<const bf16x8*>(_ab + base_f + 1536);\
    acc[0][0] = __builtin_amdgcn_mfma_f32_16x16x32_bf16(_f0, BIN[0], acc[0][0], 0, 0, 0); \
    acc[0][1] = __builtin_amdgcn_mfma_f32_16x16x32_bf16(_f0, BIN[1], acc[0][1], 0, 0, 0); \
    acc[0][2] = __builtin_amdgcn_mfma_f32_16x16x32_bf16(_f0, BIN[2], acc[0][2], 0, 0, 0); \
    acc[0][3] = __builtin_amdgcn_mfma_f32_16x16x32_bf16(_f0, BIN[3], acc[0][3], 0, 0, 0); \
    acc[1][0] = __builtin_amdgcn_mfma_f32_16x16x32_bf16(_f1, BIN[0], acc[1][0], 0, 0, 0); \
    acc[1][1] = __builtin_amdgcn_mfma_f32_16x16x32_bf16(_f1, BIN[1], acc[1][1], 0, 0, 0); \
    acc[1][2] = __builtin_amdgcn_mfma_f32_16x16x32_bf16(_f1, BIN[2], acc[1][2], 0, 0, 0); \
    acc[1][3] = __builtin_amdgcn_mfma_f32_16x16x32_bf16(_f1, BIN[3], acc[1][3], 0, 0, 0); \
    acc[2][0] = __builtin_amdgcn_mfma_f32_16x16x32_bf16(_f2, BIN[0], acc[2][0], 0, 0, 0); \
    acc[2][1] = __builtin_amdgcn_mfma_f32_16x16x32_bf16(_f2, BIN[1], acc[2][1], 0, 0, 0); \
    acc[2][2] = __builtin_amdgcn_mfma_f32_16x16x32_bf16(_f2, BIN[2], acc[2][2], 0, 0, 0); \
    acc[2][3] = __builtin_amdgcn_mfma_f32_16x16x32_bf16(_f2, BIN[3], acc[2][3], 0, 0, 0); \
    acc[3][0] = __builtin_amdgcn_mfma_f32_16x16x32_bf16(_f3, BIN[0], acc[3][0], 0, 0, 0); \
    acc[3][1] = __builtin_amdgcn_mfma_f32_16x16x32_bf16(_f3, BIN[1], acc[3][1], 0, 0, 0); \
    acc[3][2] = __builtin_amdgcn_mfma_f32_16x16x32_bf16(_f3, BIN[2], acc[3][2], 0, 0, 0); \
    acc[3][3] = __builtin_amdgcn_mfma_f32_16x16x32_bf16(_f3, BIN[3], acc[3][3], 0, 0, 0); \
    if (DO_CVT) CVT4W(((J) + 1) & 3, RAWIN);                          \
    asm volatile("s_waitcnt lgkmcnt(0)" ::: "memory");                \
  }

  // prologue: A(0) -> buf0; A(1) -> rawO; B(0) -> Ba
  {
    f32x4 raw0 = gp[0];
    CVT4W(0, raw0);
  }
  rawO = gp[8];
  LOADB(Ba, 0);
  __syncthreads();

#pragma unroll 1
  for (int p = 0; p < 15; ++p) {
    const int j = p * 2;
    K_ITER(j,     rawO, rawE, Ba, Bb, 1, 1, 1);   // gload A(j+2), B(j+1), cvt A(j+1)
    K_ITER(j + 1, rawE, rawO, Bb, Ba, 1, 1, 1);   // gload A(j+3), B(j+2), cvt A(j+2)
  }
  K_ITER(30, rawO, rawE, Ba, Bb, 0, 1, 1);        // B(31), cvt A(31)->buf3
  K_ITER(31, rawE, rawO, Bb, Ba, 0, 0, 0);        // last: frags buf3, MFMA B(31)

#undef K_ITER
#undef LOADB
#undef CVT4W

  // epilogue: x = acc + P[b][h]; part += v[h]*tanh(x); reduce over hl lanes
  float part[4][4];
#pragma unroll
  for (int mi = 0; mi < 4; ++mi)
#pragma unroll
    for (int rr = 0; rr < 4; ++rr) part[mi][rr] = 0.f;

#pragma unroll
  for (int ni = 0; ni < 4; ++ni) {
    const int h = w * 64 + ni * 16 + hl;
    const float ph = P[b * 512 + h];
    const float vh = v[h];
#pragma unroll
    for (int mi = 0; mi < 4; ++mi)
#pragma unroll
      for (int rr = 0; rr < 4; ++rr) {
        float x = acc[mi][ni][rr] + ph;
        float e = __expf(2.f * x);
        part[mi][rr] += vh * (1.f - 2.f * __frcp_rn(e + 1.f));
      }
  }
#pragma unroll
  for (int off = 1; off < 16; off <<= 1)
#pragma unroll
    for (int mi = 0; mi < 4; ++mi)
#pragma unroll
      for (int rr = 0; rr < 4; ++rr)
        part[mi][rr] += __shfl_xor(part[mi][rr], off, 16);

  if (hl == 0) {
#pragma unroll
    for (int mi = 0; mi < 4; ++mi)
#pragma unroll
      for (int rr = 0; rr < 4; ++rr)
        attred[mi * 16 + kg * 4 + rr][w] = part[mi][rr];
  }
  __syncthreads();
  if (tid < 64) {
    const float* a = attred[tid];
    logits[rowbase + tid] = ((a[0] + a[1]) + (a[2] + a[3])) +
                            ((a[4] + a[5]) + (a[6] + a[7]));
  }
}

// ---- K2: softmax over S=4096 per batch row
__global__ __launch_bounds__(256) void k_softmax(
    const float* __restrict__ logits, float* __restrict__ out) {
  const int b = blockIdx.x;
  const int t = threadIdx.x;
  const int wid = t >> 6, lane = t & 63;
  const float* L = logits + b * 4096;
  __shared__ float rmax[4], rsum[4];
  float lv[16];
  float m = -1e30f;
#pragma unroll
  for (int i = 0; i < 16; ++i) {
    lv[i] = L[t + i * 256];
    m = fmaxf(m, lv[i]);
  }
#pragma unroll
  for (int off = 32; off >= 1; off >>= 1) m = fmaxf(m, __shfl_xor(m, off));
  if (lane == 0) rmax[wid] = m;
  __syncthreads();
  m = fmaxf(fmaxf(rmax[0], rmax[1]), fmaxf(rmax[2], rmax[3]));
  float s = 0.f;
#pragma unroll
  for (int i = 0; i < 16; ++i) {
    lv[i] = __expf(lv[i] - m);
    s += lv[i];
  }
#pragma unroll
  for (int off = 32; off >= 1; off >>= 1) s += __shfl_xor(s, off);
  if (lane == 0) rsum[wid] = s;
  __syncthreads();
  s = rsum[0] + rsum[1] + rsum[2] + rsum[3];
  float inv = 1.0f / s;
#pragma unroll
  for (int i = 0; i < 16; ++i) out[b * 4096 + t + i * 256] = lv[i] * inv;
}

extern "C" void kernel_launch(void* const* d_in, const int* in_sizes, int n_in,
                              void* d_out, int out_size, void* d_ws, size_t ws_size,
                              hipStream_t stream) {
  const float* hidden = (const float*)d_in[0];   // [16,512]
  const float* enc    = (const float*)d_in[1];   // [16,4096,1024]
  const float* W      = (const float*)d_in[2];   // [512,1536]
  const float* bias   = (const float*)d_in[3];   // [512]
  const float* v      = (const float*)d_in[4];   // [512]
  float* out = (float*)d_out;                    // [16,4096]

  char* ws = (char*)d_ws;
  float* P = (float*)ws;                                       // 32 KB
  unsigned short* W2t = (unsigned short*)(ws + 32768);         // 1 MB
  float* logits = (float*)(ws + 32768 + 1048576);              // 256 KB

  k_prep<<<288, 256, 0, stream>>>(W, hidden, bias, W2t, P);
  k_main<<<1024, 512, 0, stream>>>(enc, (const short*)W2t, P, v, logits);
  k_softmax<<<16, 256, 0, stream>>>(logits, out);
}